// Round 11
// baseline (62.867 us; speedup 1.0000x reference)
//
#include <hip/hip_runtime.h>

#define N_AB  1024
#define NHALF 1025
#define NFULL 2049
#define HDIM  64
#define PLANE ((size_t)N_AB * NFULL)

typedef __bf16 bf16x8 __attribute__((ext_vector_type(8)));
typedef __bf16 bf16x4 __attribute__((ext_vector_type(4)));
typedef float  f32x4  __attribute__((ext_vector_type(4)));
typedef float  f32x2  __attribute__((ext_vector_type(2)));

#define MFMA16(A,B,C) __builtin_amdgcn_mfma_f32_16x16x32_bf16(A,B,C,0,0,0)

// Clamped odd Pade [5/5] tanh on a packed pair. Only ONE transcendental (rcp)
// per element vs exp2+rcp before. |err| <= ~1.8e-3 (clamp at 3.5), far under
// the bf16-fragment rounding that dominates absmax. Z2: input pair (raw z).
// Yields H2 = tanh(z), OMH2 = 1 - H2^2 (tangent factor).
#define RAT2(Z2,H2,OMH2) { \
    f32x2 _z = __builtin_elementwise_min(__builtin_elementwise_max(Z2, _km35), _k35); \
    f32x2 _s = _z * _z; \
    f32x2 _nn = __builtin_elementwise_fma(_s, _s + _k105, _k945); \
    f32x2 _dd = __builtin_elementwise_fma(_s, __builtin_elementwise_fma(_s, _k15, _k420), _k945); \
    f32x2 _r; _r.x = __builtin_amdgcn_rcpf(_dd.x); _r.y = __builtin_amdgcn_rcpf(_dd.y); \
    H2 = (_z * _nn) * _r; \
    OMH2 = __builtin_elementwise_fma(-H2, H2, _k1); }

// layer-1 element pair: W2_=w0 (raw), B2_=b0 (raw); h -> BV, (1-h^2)*w0 -> BT
#define L1P(I0, W2_, B2_, BV, BT) { \
    f32x2 _zin = __builtin_elementwise_fma(W2_, x2, B2_); \
    f32x2 _h, _omh; RAT2(_zin,_h,_omh) \
    f32x2 _bt = _omh * W2_; \
    BV[I0] = (__bf16)_h.x; BV[I0+1] = (__bf16)_h.y; \
    BT[I0] = (__bf16)_bt.x; BT[I0+1] = (__bf16)_bt.y; }

// layer-2 element pair: AV2=z2pre, AT2=dz2pre, B1_=b1 (raw); accumulate L3 partials.
// dh = (1-h^2)*dacc exactly (no deferred *4 factor any more).
#define L2P(AV2, AT2, B1_, W20_2, W21_2) { \
    f32x2 _zin = AV2 + B1_; \
    f32x2 _h, _omh; RAT2(_zin,_h,_omh) \
    f32x2 _dh = _omh * (AT2); \
    pv0_2 = __builtin_elementwise_fma(W20_2, _h,  pv0_2); \
    pv1_2 = __builtin_elementwise_fma(W21_2, _h,  pv1_2); \
    pt0_2 = __builtin_elementwise_fma(W20_2, _dh, pt0_2); \
    pt1_2 = __builtin_elementwise_fma(W21_2, _dh, pt1_2); }

#define L2QUAD(AV,AT,B1,WR0,WR1) \
    L2P(AV.xy, AT.xy, B1.xy, WR0.xy, WR1.xy) \
    L2P(AV.zw, AT.zw, B1.zw, WR0.zw, WR1.zw)

// full per-point-tile pipeline; leaves xp,yp,xpp,ypp in scope
#define COMPUTE_TILE(XV) \
    const float x = (XV); \
    const f32x2 x2 = {x, x}; \
    const float sa = __sinf(x), ca = __cosf(x); \
    const float cam1 = ca - 1.0f; \
    bf16x8 bv0, bv1, bt0, bt1; \
    L1P(0, w0A.xy, b0A.xy, bv0, bt0) \
    L1P(2, w0A.zw, b0A.zw, bv0, bt0) \
    L1P(4, w0B.xy, b0B.xy, bv0, bt0) \
    L1P(6, w0B.zw, b0B.zw, bv0, bt0) \
    L1P(0, w0C.xy, b0C.xy, bv1, bt1) \
    L1P(2, w0C.zw, b0C.zw, bv1, bt1) \
    L1P(4, w0D.xy, b0D.xy, bv1, bt1) \
    L1P(6, w0D.zw, b0D.zw, bv1, bt1) \
    const f32x4 zz = {0.0f,0.0f,0.0f,0.0f}; \
    f32x4 av0 = MFMA16(A01,bv1,MFMA16(A00,bv0,zz)); \
    f32x4 av1 = MFMA16(A11,bv1,MFMA16(A10,bv0,zz)); \
    f32x4 av2 = MFMA16(A21,bv1,MFMA16(A20,bv0,zz)); \
    f32x4 av3 = MFMA16(A31,bv1,MFMA16(A30,bv0,zz)); \
    f32x4 at0 = MFMA16(A01,bt1,MFMA16(A00,bt0,zz)); \
    f32x4 at1 = MFMA16(A11,bt1,MFMA16(A10,bt0,zz)); \
    f32x4 at2 = MFMA16(A21,bt1,MFMA16(A20,bt0,zz)); \
    f32x4 at3 = MFMA16(A31,bt1,MFMA16(A30,bt0,zz)); \
    f32x2 pv0_2 = {0.0f,0.0f}, pv1_2 = {0.0f,0.0f}; \
    f32x2 pt0_2 = {0.0f,0.0f}, pt1_2 = {0.0f,0.0f}; \
    L2QUAD(av0,at0,b1q0,w2a0,w2b0) \
    L2QUAD(av1,at1,b1q1,w2a1,w2b1) \
    L2QUAD(av2,at2,b1q2,w2a2,w2b2) \
    L2QUAD(av3,at3,b1q3,w2a3,w2b3) \
    float pv0 = pv0_2.x + pv0_2.y, pv1 = pv1_2.x + pv1_2.y; \
    float pt0 = pt0_2.x + pt0_2.y, pt1 = pt1_2.x + pt1_2.y; \
    pv0 += __shfl_xor(pv0,16); pv0 += __shfl_xor(pv0,32); \
    pv1 += __shfl_xor(pv1,16); pv1 += __shfl_xor(pv1,32); \
    pt0 += __shfl_xor(pt0,16); pt0 += __shfl_xor(pt0,32); \
    pt1 += __shfl_xor(pt1,16); pt1 += __shfl_xor(pt1,32); \
    const float z0 = pv0 + b20, z1 = pv1 + b21; \
    const float aa = z0*z0, bb = z1*z1; \
    const float da = 2.0f*z0*pt0, db = 2.0f*z1*pt1; \
    const float xp = aa*cam1, yp = bb*sa; \
    const float xpp = fmaf(da,cam1,-(aa*sa)); \
    const float ypp = fmaf(bb,ca, db*sa);

__global__ void __launch_bounds__(256, 2) sofa_kernel(
    const float* __restrict__ alpha,
    const float* __restrict__ w0,
    const float* __restrict__ w1,
    const float* __restrict__ w2,
    const float* __restrict__ b0,
    const float* __restrict__ b1,
    const float* __restrict__ b2,
    float* __restrict__ out)
{
    __shared__ __align__(16) __bf16 w1s[HDIM * HDIM];   // XOR-swizzled bf16 W1
    __shared__ float s_alpha[NHALF];
    __shared__ float s_xplast;

    const int n    = blockIdx.x;
    const int tid  = threadIdx.x;
    const int lane = tid & 63;
    const int wid  = tid >> 6;
    const int col  = lane & 15;   // MFMA col (point) / A-row index
    const int grp  = lane >> 4;   // k-slot group / output-plane selector

    const float* __restrict__ w0n = w0 + (size_t)n * HDIM;
    const float* __restrict__ b0n = b0 + (size_t)n * HDIM;
    const float* __restrict__ w1n = w1 + (size_t)n * HDIM * HDIM;
    const float* __restrict__ b1n = b1 + (size_t)n * HDIM;
    const float* __restrict__ w2n = w2 + (size_t)n * 2 * HDIM;
    const float* __restrict__ b2n = b2 + (size_t)n * 2;

    // ---- stage alpha (fp32) and W1 (bf16, 16B-group XOR swizzle) into LDS ----
    for (int e = tid; e < NHALF; e += 256) s_alpha[e] = alpha[e];
    for (int e4 = tid; e4 < (HDIM * HDIM) / 4; e4 += 256) {
        const int i = e4 >> 4, j4 = (e4 & 15) << 2;
        f32x4 v = ((const f32x4*)w1n)[e4];
        bf16x4 b;
        b[0] = (__bf16)v.x; b[1] = (__bf16)v.y; b[2] = (__bf16)v.z; b[3] = (__bf16)v.w;
        *(bf16x4*)&w1s[i * 64 + (((j4 >> 3) ^ (i & 7)) << 3) + (j4 & 7)] = b;
    }
    __syncthreads();

    // ---- constants for packed rational tanh ----
    const f32x2 _k1   = {  1.0f,   1.0f};
    const f32x2 _k35  = {  3.5f,   3.5f};
    const f32x2 _km35 = { -3.5f,  -3.5f};
    const f32x2 _k105 = {105.0f, 105.0f};
    const f32x2 _k945 = {945.0f, 945.0f};
    const f32x2 _k420 = {420.0f, 420.0f};
    const f32x2 _k15  = { 15.0f,  15.0f};

    // ---- per-lane hoisted constants (raw weights; no prescales needed) ----
    const int jb0 = grp * 8, jb1 = 32 + grp * 8;
    const f32x4 w0A = *(const f32x4*)(w0n + jb0);
    const f32x4 w0B = *(const f32x4*)(w0n + jb0 + 4);
    const f32x4 w0C = *(const f32x4*)(w0n + jb1);
    const f32x4 w0D = *(const f32x4*)(w0n + jb1 + 4);
    const f32x4 b0A = *(const f32x4*)(b0n + jb0);
    const f32x4 b0B = *(const f32x4*)(b0n + jb0 + 4);
    const f32x4 b0C = *(const f32x4*)(b0n + jb1);
    const f32x4 b0D = *(const f32x4*)(b0n + jb1 + 4);

    const f32x4 b1q0 = *(const f32x4*)(b1n + 0  + grp * 4);
    const f32x4 b1q1 = *(const f32x4*)(b1n + 16 + grp * 4);
    const f32x4 b1q2 = *(const f32x4*)(b1n + 32 + grp * 4);
    const f32x4 b1q3 = *(const f32x4*)(b1n + 48 + grp * 4);

    const f32x4 w2a0 = *(const f32x4*)(w2n + 0  + grp * 4);
    const f32x4 w2a1 = *(const f32x4*)(w2n + 16 + grp * 4);
    const f32x4 w2a2 = *(const f32x4*)(w2n + 32 + grp * 4);
    const f32x4 w2a3 = *(const f32x4*)(w2n + 48 + grp * 4);
    const f32x4 w2b0 = *(const f32x4*)(w2n + 64 + 0  + grp * 4);
    const f32x4 w2b1 = *(const f32x4*)(w2n + 64 + 16 + grp * 4);
    const f32x4 w2b2 = *(const f32x4*)(w2n + 64 + 32 + grp * 4);
    const f32x4 w2b3 = *(const f32x4*)(w2n + 64 + 48 + grp * 4);
    const float b20 = b2n[0], b21 = b2n[1];

    // ---- A-fragments: W1 rows in registers (lane: row=col, k = 32*KH + 8*grp + 0..7) ----
    const bf16x8* w1v = (const bf16x8*)w1s;
    const int sw = col & 7;
#define AF(RT,KH) w1v[((RT)*16 + col)*8 + (((KH)*4 + grp) ^ sw)]
    const bf16x8 A00 = AF(0,0), A01 = AF(0,1), A10 = AF(1,0), A11 = AF(1,1);
    const bf16x8 A20 = AF(2,0), A21 = AF(2,1), A30 = AF(3,0), A31 = AF(3,1);

    const size_t obase = (size_t)grp * PLANE + (size_t)n * NFULL;

    // ---- point 1024 first (wave 0), to get xp_last for the xp mirror ----
    if (wid == 0) {
        COMPUTE_TILE(s_alpha[1024])
        if (col == 0) {
            out[obase + 1024] = (grp == 0) ? xp : (grp == 1) ? yp : (grp == 2) ? xpp : ypp;
            if (grp == 0) s_xplast = xp;
        }
    }
    __syncthreads();
    const float xl2 = 2.0f * s_xplast;

    // ---- main loop: 16 iters/wave, 16 points each; covers b = 0..1023 ----
    #pragma unroll 1
    for (int it = 0; it < 16; ++it) {
        const int p = ((it * 4 + wid) << 4) + col;
        COMPUTE_TILE(s_alpha[p])
        const float vdir = (grp == 0) ? xp : (grp == 1) ? yp : (grp == 2) ? xpp : ypp;
        const float vmir = (grp == 0) ? (xl2 - xp)
                         : (grp == 1) ? yp
                         : (grp == 2) ? xpp : -ypp;
        out[obase + p] = vdir;
        out[obase + (2048 - p)] = vmir;
    }
}

extern "C" void kernel_launch(void* const* d_in, const int* in_sizes, int n_in,
                              void* d_out, int out_size, void* d_ws, size_t ws_size,
                              hipStream_t stream) {
    const float* alpha = (const float*)d_in[0];
    const float* w0    = (const float*)d_in[1];
    const float* w1    = (const float*)d_in[2];
    const float* w2    = (const float*)d_in[3];
    const float* b0    = (const float*)d_in[4];
    const float* b1    = (const float*)d_in[5];
    const float* b2    = (const float*)d_in[6];
    float* out = (float*)d_out;
    sofa_kernel<<<dim3(N_AB), dim3(256), 0, stream>>>(alpha, w0, w1, w2, b0, b1, b2, out);
}

// Round 12
// 54.157 us; speedup vs baseline: 1.1608x; 1.1608x over previous
//
#include <hip/hip_runtime.h>

#define N_AB  1024
#define NHALF 1025
#define NFULL 2049
#define HDIM  64
#define PLANE ((size_t)N_AB * NFULL)
#define C2L   2.8853900817779268f   // 2*log2(e), used only for table staging

typedef __bf16 bf16x8 __attribute__((ext_vector_type(8)));
typedef __bf16 bf16x4 __attribute__((ext_vector_type(4)));
typedef float  f32x4  __attribute__((ext_vector_type(4)));
typedef float  f32x2  __attribute__((ext_vector_type(2)));

#define MFMA16(A,B,C) __builtin_amdgcn_mfma_f32_16x16x32_bf16(A,B,C,0,0,0)

// LDS-table tanh on a packed pair. z quantized to 1/256 grid on [-4,4] (clamped
// via single v_med3_f32 per element), h = tanh(z_q) from 2048-entry table
// (ds_read_b32 gather -> DS pipe, VALU freed). omh = 1 - h^2 is the EXACT
// derivative at z_q (self-consistent). |h err| <= 2e-3; clamp tail <= 6.7e-4.
#define TBL2(Z2,H2,OMH2) { \
    float _f0 = fmaf(Z2.x, 256.0f, 1024.5f); \
    float _f1 = fmaf(Z2.y, 256.0f, 1024.5f); \
    _f0 = __builtin_amdgcn_fmed3f(_f0, 0.5f, 2047.0f); \
    _f1 = __builtin_amdgcn_fmed3f(_f1, 0.5f, 2047.0f); \
    H2.x = s_tanh[(int)_f0]; \
    H2.y = s_tanh[(int)_f1]; \
    OMH2 = __builtin_elementwise_fma(-H2, H2, _k1); }

// layer-1 element pair: W2_=w0 (raw), B2_=b0 (raw); h -> BV, (1-h^2)*w0 -> BT
#define L1P(I0, W2_, B2_, BV, BT) { \
    f32x2 _zin = __builtin_elementwise_fma(W2_, x2, B2_); \
    f32x2 _h, _omh; TBL2(_zin,_h,_omh) \
    f32x2 _bt = _omh * W2_; \
    BV[I0] = (__bf16)_h.x; BV[I0+1] = (__bf16)_h.y; \
    BT[I0] = (__bf16)_bt.x; BT[I0+1] = (__bf16)_bt.y; }

// layer-2 element pair: AV2=z2pre, AT2=dz2pre, B1_=b1 (raw); accumulate L3 partials.
#define L2P(AV2, AT2, B1_, W20_2, W21_2) { \
    f32x2 _zin = AV2 + B1_; \
    f32x2 _h, _omh; TBL2(_zin,_h,_omh) \
    f32x2 _dh = _omh * (AT2); \
    pv0_2 = __builtin_elementwise_fma(W20_2, _h,  pv0_2); \
    pv1_2 = __builtin_elementwise_fma(W21_2, _h,  pv1_2); \
    pt0_2 = __builtin_elementwise_fma(W20_2, _dh, pt0_2); \
    pt1_2 = __builtin_elementwise_fma(W21_2, _dh, pt1_2); }

#define L2QUAD(AV,AT,B1,WR0,WR1) \
    L2P(AV.xy, AT.xy, B1.xy, WR0.xy, WR1.xy) \
    L2P(AV.zw, AT.zw, B1.zw, WR0.zw, WR1.zw)

// full per-point-tile pipeline; leaves xp,yp,xpp,ypp in scope
#define COMPUTE_TILE(XV) \
    const float x = (XV); \
    const f32x2 x2 = {x, x}; \
    const float sa = __sinf(x), ca = __cosf(x); \
    const float cam1 = ca - 1.0f; \
    bf16x8 bv0, bv1, bt0, bt1; \
    L1P(0, w0A.xy, b0A.xy, bv0, bt0) \
    L1P(2, w0A.zw, b0A.zw, bv0, bt0) \
    L1P(4, w0B.xy, b0B.xy, bv0, bt0) \
    L1P(6, w0B.zw, b0B.zw, bv0, bt0) \
    L1P(0, w0C.xy, b0C.xy, bv1, bt1) \
    L1P(2, w0C.zw, b0C.zw, bv1, bt1) \
    L1P(4, w0D.xy, b0D.xy, bv1, bt1) \
    L1P(6, w0D.zw, b0D.zw, bv1, bt1) \
    const f32x4 zz = {0.0f,0.0f,0.0f,0.0f}; \
    f32x4 av0 = MFMA16(A01,bv1,MFMA16(A00,bv0,zz)); \
    f32x4 av1 = MFMA16(A11,bv1,MFMA16(A10,bv0,zz)); \
    f32x4 av2 = MFMA16(A21,bv1,MFMA16(A20,bv0,zz)); \
    f32x4 av3 = MFMA16(A31,bv1,MFMA16(A30,bv0,zz)); \
    f32x4 at0 = MFMA16(A01,bt1,MFMA16(A00,bt0,zz)); \
    f32x4 at1 = MFMA16(A11,bt1,MFMA16(A10,bt0,zz)); \
    f32x4 at2 = MFMA16(A21,bt1,MFMA16(A20,bt0,zz)); \
    f32x4 at3 = MFMA16(A31,bt1,MFMA16(A30,bt0,zz)); \
    f32x2 pv0_2 = {0.0f,0.0f}, pv1_2 = {0.0f,0.0f}; \
    f32x2 pt0_2 = {0.0f,0.0f}, pt1_2 = {0.0f,0.0f}; \
    L2QUAD(av0,at0,b1q0,w2a0,w2b0) \
    L2QUAD(av1,at1,b1q1,w2a1,w2b1) \
    L2QUAD(av2,at2,b1q2,w2a2,w2b2) \
    L2QUAD(av3,at3,b1q3,w2a3,w2b3) \
    float pv0 = pv0_2.x + pv0_2.y, pv1 = pv1_2.x + pv1_2.y; \
    float pt0 = pt0_2.x + pt0_2.y, pt1 = pt1_2.x + pt1_2.y; \
    pv0 += __shfl_xor(pv0,16); pv0 += __shfl_xor(pv0,32); \
    pv1 += __shfl_xor(pv1,16); pv1 += __shfl_xor(pv1,32); \
    pt0 += __shfl_xor(pt0,16); pt0 += __shfl_xor(pt0,32); \
    pt1 += __shfl_xor(pt1,16); pt1 += __shfl_xor(pt1,32); \
    const float z0 = pv0 + b20, z1 = pv1 + b21; \
    const float aa = z0*z0, bb = z1*z1; \
    const float da = 2.0f*z0*pt0, db = 2.0f*z1*pt1; \
    const float xp = aa*cam1, yp = bb*sa; \
    const float xpp = fmaf(da,cam1,-(aa*sa)); \
    const float ypp = fmaf(bb,ca, db*sa);

__global__ void __launch_bounds__(256, 2) sofa_kernel(
    const float* __restrict__ alpha,
    const float* __restrict__ w0,
    const float* __restrict__ w1,
    const float* __restrict__ w2,
    const float* __restrict__ b0,
    const float* __restrict__ b1,
    const float* __restrict__ b2,
    float* __restrict__ out)
{
    __shared__ __align__(16) __bf16 w1s[HDIM * HDIM];   // XOR-swizzled bf16 W1
    __shared__ float s_alpha[NHALF];
    __shared__ __align__(16) float s_tanh[2048];        // tanh((i-1024)/256), i=0..2047
    __shared__ float s_xplast;

    const int n    = blockIdx.x;
    const int tid  = threadIdx.x;
    const int lane = tid & 63;
    const int wid  = tid >> 6;
    const int col  = lane & 15;   // MFMA col (point) / A-row index
    const int grp  = lane >> 4;   // k-slot group / output-plane selector

    const float* __restrict__ w0n = w0 + (size_t)n * HDIM;
    const float* __restrict__ b0n = b0 + (size_t)n * HDIM;
    const float* __restrict__ w1n = w1 + (size_t)n * HDIM * HDIM;
    const float* __restrict__ b1n = b1 + (size_t)n * HDIM;
    const float* __restrict__ w2n = w2 + (size_t)n * 2 * HDIM;
    const float* __restrict__ b2n = b2 + (size_t)n * 2;

    // ---- stage alpha, tanh table, and W1 (bf16, XOR swizzle) into LDS ----
    for (int e = tid; e < NHALF; e += 256) s_alpha[e] = alpha[e];
    for (int e = tid; e < 2048; e += 256) {
        const float z = (float)(e - 1024) * 0.00390625f;     // 1/256
        const float ee = __builtin_amdgcn_exp2f(z * C2L);
        s_tanh[e] = fmaf(-2.0f, __builtin_amdgcn_rcpf(1.0f + ee), 1.0f);  // tanh(z)
    }
    for (int e4 = tid; e4 < (HDIM * HDIM) / 4; e4 += 256) {
        const int i = e4 >> 4, j4 = (e4 & 15) << 2;
        f32x4 v = ((const f32x4*)w1n)[e4];
        bf16x4 b;
        b[0] = (__bf16)v.x; b[1] = (__bf16)v.y; b[2] = (__bf16)v.z; b[3] = (__bf16)v.w;
        *(bf16x4*)&w1s[i * 64 + (((j4 >> 3) ^ (i & 7)) << 3) + (j4 & 7)] = b;
    }
    __syncthreads();

    // ---- constants for packed math ----
    const f32x2 _k1 = {1.0f, 1.0f};

    // ---- per-lane hoisted constants (raw weights; no prescales) ----
    const int jb0 = grp * 8, jb1 = 32 + grp * 8;
    const f32x4 w0A = *(const f32x4*)(w0n + jb0);
    const f32x4 w0B = *(const f32x4*)(w0n + jb0 + 4);
    const f32x4 w0C = *(const f32x4*)(w0n + jb1);
    const f32x4 w0D = *(const f32x4*)(w0n + jb1 + 4);
    const f32x4 b0A = *(const f32x4*)(b0n + jb0);
    const f32x4 b0B = *(const f32x4*)(b0n + jb0 + 4);
    const f32x4 b0C = *(const f32x4*)(b0n + jb1);
    const f32x4 b0D = *(const f32x4*)(b0n + jb1 + 4);

    const f32x4 b1q0 = *(const f32x4*)(b1n + 0  + grp * 4);
    const f32x4 b1q1 = *(const f32x4*)(b1n + 16 + grp * 4);
    const f32x4 b1q2 = *(const f32x4*)(b1n + 32 + grp * 4);
    const f32x4 b1q3 = *(const f32x4*)(b1n + 48 + grp * 4);

    const f32x4 w2a0 = *(const f32x4*)(w2n + 0  + grp * 4);
    const f32x4 w2a1 = *(const f32x4*)(w2n + 16 + grp * 4);
    const f32x4 w2a2 = *(const f32x4*)(w2n + 32 + grp * 4);
    const f32x4 w2a3 = *(const f32x4*)(w2n + 48 + grp * 4);
    const f32x4 w2b0 = *(const f32x4*)(w2n + 64 + 0  + grp * 4);
    const f32x4 w2b1 = *(const f32x4*)(w2n + 64 + 16 + grp * 4);
    const f32x4 w2b2 = *(const f32x4*)(w2n + 64 + 32 + grp * 4);
    const f32x4 w2b3 = *(const f32x4*)(w2n + 64 + 48 + grp * 4);
    const float b20 = b2n[0], b21 = b2n[1];

    // ---- A-fragments: W1 rows in registers (lane: row=col, k = 32*KH + 8*grp + 0..7) ----
    const bf16x8* w1v = (const bf16x8*)w1s;
    const int sw = col & 7;
#define AF(RT,KH) w1v[((RT)*16 + col)*8 + (((KH)*4 + grp) ^ sw)]
    const bf16x8 A00 = AF(0,0), A01 = AF(0,1), A10 = AF(1,0), A11 = AF(1,1);
    const bf16x8 A20 = AF(2,0), A21 = AF(2,1), A30 = AF(3,0), A31 = AF(3,1);

    const size_t obase = (size_t)grp * PLANE + (size_t)n * NFULL;

    // ---- point 1024 first (wave 0), to get xp_last for the xp mirror ----
    if (wid == 0) {
        COMPUTE_TILE(s_alpha[1024])
        if (col == 0) {
            out[obase + 1024] = (grp == 0) ? xp : (grp == 1) ? yp : (grp == 2) ? xpp : ypp;
            if (grp == 0) s_xplast = xp;
        }
    }
    __syncthreads();
    const float xl2 = 2.0f * s_xplast;

    // ---- main loop: 16 iters/wave, 16 points each; covers b = 0..1023 ----
    #pragma unroll 1
    for (int it = 0; it < 16; ++it) {
        const int p = ((it * 4 + wid) << 4) + col;
        COMPUTE_TILE(s_alpha[p])
        const float vdir = (grp == 0) ? xp : (grp == 1) ? yp : (grp == 2) ? xpp : ypp;
        const float vmir = (grp == 0) ? (xl2 - xp)
                         : (grp == 1) ? yp
                         : (grp == 2) ? xpp : -ypp;
        out[obase + p] = vdir;
        out[obase + (2048 - p)] = vmir;
    }
}

extern "C" void kernel_launch(void* const* d_in, const int* in_sizes, int n_in,
                              void* d_out, int out_size, void* d_ws, size_t ws_size,
                              hipStream_t stream) {
    const float* alpha = (const float*)d_in[0];
    const float* w0    = (const float*)d_in[1];
    const float* w1    = (const float*)d_in[2];
    const float* w2    = (const float*)d_in[3];
    const float* b0    = (const float*)d_in[4];
    const float* b1    = (const float*)d_in[5];
    const float* b2    = (const float*)d_in[6];
    float* out = (float*)d_out;
    sofa_kernel<<<dim3(N_AB), dim3(256), 0, stream>>>(alpha, w0, w1, w2, b0, b1, b2, out);
}

// Round 13
// 51.232 us; speedup vs baseline: 1.2271x; 1.0571x over previous
//
#include <hip/hip_runtime.h>

#define N_AB  1024
#define NHALF 1025
#define NFULL 2049
#define HDIM  64
#define PLANE ((size_t)N_AB * NFULL)
#define C2L   2.8853900817779268f   // 2*log2(e), used only for table staging

typedef __bf16 bf16x8 __attribute__((ext_vector_type(8)));
typedef __bf16 bf16x4 __attribute__((ext_vector_type(4)));
typedef float  f32x4  __attribute__((ext_vector_type(4)));
typedef float  f32x2  __attribute__((ext_vector_type(2)));

#define MFMA16(A,B,C) __builtin_amdgcn_mfma_f32_16x16x32_bf16(A,B,C,0,0,0)

// Table lookup from a PRECOMPUTED index pair (f32, already 256*z + 1024.5).
// med3 clamps to [0.5, 2047]; trunc -> gather from s_tanh (DS pipe).
#define TBLIDX2(IX2,H2,OMH2) { \
    float _f0 = __builtin_amdgcn_fmed3f(IX2.x, 0.5f, 2047.0f); \
    float _f1 = __builtin_amdgcn_fmed3f(IX2.y, 0.5f, 2047.0f); \
    H2.x = s_tanh[(int)_f0]; \
    H2.y = s_tanh[(int)_f1]; \
    OMH2 = __builtin_elementwise_fma(-H2, H2, _k1); }

// layer-1 element pair: WI2=256*w0, BI2=256*b0+1024.5 (index affine pre-folded),
// WD2=w0/256 (tangent scale compensating the 256x A-fragments).
// h (raw) -> BV ; omh*w0/256 -> BT
#define L1P(I0, WI2, BI2, WD2, BV, BT) { \
    f32x2 _ix = __builtin_elementwise_fma(WI2, x2, BI2); \
    f32x2 _h, _omh; TBLIDX2(_ix,_h,_omh) \
    f32x2 _bt = _omh * WD2; \
    BV[I0] = (__bf16)_h.x; BV[I0+1] = (__bf16)_h.y; \
    BT[I0] = (__bf16)_bt.x; BT[I0+1] = (__bf16)_bt.y; }

// layer-2 element pair: AVI2 = MFMA output = 256*(W1 h) + 256*b1 + 1024.5 (index
// directly, b1 affine folded into the MFMA C-input). AT2 = raw tangent pre-act.
#define L2P(AVI2, AT2, W20_2, W21_2) { \
    f32x2 _h, _omh; TBLIDX2(AVI2,_h,_omh) \
    f32x2 _dh = _omh * (AT2); \
    pv0_2 = __builtin_elementwise_fma(W20_2, _h,  pv0_2); \
    pv1_2 = __builtin_elementwise_fma(W21_2, _h,  pv1_2); \
    pt0_2 = __builtin_elementwise_fma(W20_2, _dh, pt0_2); \
    pt1_2 = __builtin_elementwise_fma(W21_2, _dh, pt1_2); }

#define L2QUAD(AV,AT,WR0,WR1) \
    L2P(AV.xy, AT.xy, WR0.xy, WR1.xy) \
    L2P(AV.zw, AT.zw, WR0.zw, WR1.zw)

// full per-point-tile pipeline; leaves xp,yp,xpp,ypp in scope
#define COMPUTE_TILE(P) \
    const f32x4 tg = s_trig[P]; \
    const float x = tg.x, sa = tg.y, cam1 = tg.z, ca = tg.w; \
    const f32x2 x2 = {x, x}; \
    bf16x8 bv0, bv1, bt0, bt1; \
    L1P(0, w0iA.xy, b0iA.xy, w0dA.xy, bv0, bt0) \
    L1P(2, w0iA.zw, b0iA.zw, w0dA.zw, bv0, bt0) \
    L1P(4, w0iB.xy, b0iB.xy, w0dB.xy, bv0, bt0) \
    L1P(6, w0iB.zw, b0iB.zw, w0dB.zw, bv0, bt0) \
    L1P(0, w0iC.xy, b0iC.xy, w0dC.xy, bv1, bt1) \
    L1P(2, w0iC.zw, b0iC.zw, w0dC.zw, bv1, bt1) \
    L1P(4, w0iD.xy, b0iD.xy, w0dD.xy, bv1, bt1) \
    L1P(6, w0iD.zw, b0iD.zw, w0dD.zw, bv1, bt1) \
    const f32x4 zz = {0.0f,0.0f,0.0f,0.0f}; \
    f32x4 av0 = MFMA16(A01,bv1,MFMA16(A00,bv0,b1i0)); \
    f32x4 av1 = MFMA16(A11,bv1,MFMA16(A10,bv0,b1i1)); \
    f32x4 av2 = MFMA16(A21,bv1,MFMA16(A20,bv0,b1i2)); \
    f32x4 av3 = MFMA16(A31,bv1,MFMA16(A30,bv0,b1i3)); \
    f32x4 at0 = MFMA16(A01,bt1,MFMA16(A00,bt0,zz)); \
    f32x4 at1 = MFMA16(A11,bt1,MFMA16(A10,bt0,zz)); \
    f32x4 at2 = MFMA16(A21,bt1,MFMA16(A20,bt0,zz)); \
    f32x4 at3 = MFMA16(A31,bt1,MFMA16(A30,bt0,zz)); \
    f32x2 pv0_2 = {0.0f,0.0f}, pv1_2 = {0.0f,0.0f}; \
    f32x2 pt0_2 = {0.0f,0.0f}, pt1_2 = {0.0f,0.0f}; \
    L2QUAD(av0,at0,w2a0,w2b0) \
    L2QUAD(av1,at1,w2a1,w2b1) \
    L2QUAD(av2,at2,w2a2,w2b2) \
    L2QUAD(av3,at3,w2a3,w2b3) \
    float pv0 = pv0_2.x + pv0_2.y, pv1 = pv1_2.x + pv1_2.y; \
    float pt0 = pt0_2.x + pt0_2.y, pt1 = pt1_2.x + pt1_2.y; \
    pv0 += __shfl_xor(pv0,16); pv0 += __shfl_xor(pv0,32); \
    pv1 += __shfl_xor(pv1,16); pv1 += __shfl_xor(pv1,32); \
    pt0 += __shfl_xor(pt0,16); pt0 += __shfl_xor(pt0,32); \
    pt1 += __shfl_xor(pt1,16); pt1 += __shfl_xor(pt1,32); \
    const float z0 = pv0 + b20, z1 = pv1 + b21; \
    const float aa = z0*z0, bb = z1*z1; \
    const float da = 2.0f*z0*pt0, db = 2.0f*z1*pt1; \
    const float xp = aa*cam1, yp = bb*sa; \
    const float xpp = fmaf(da,cam1,-(aa*sa)); \
    const float ypp = fmaf(bb,ca, db*sa);

__global__ void __launch_bounds__(256, 2) sofa_kernel(
    const float* __restrict__ alpha,
    const float* __restrict__ w0,
    const float* __restrict__ w1,
    const float* __restrict__ w2,
    const float* __restrict__ b0,
    const float* __restrict__ b1,
    const float* __restrict__ b2,
    float* __restrict__ out)
{
    __shared__ __align__(16) __bf16 w1s[HDIM * HDIM];   // XOR-swizzled bf16 of 256*W1
    __shared__ __align__(16) f32x4 s_trig[NHALF];       // {x, sin, cos-1, cos}
    __shared__ __align__(16) float s_tanh[2048];        // tanh((i-1024)/256)
    __shared__ float s_xplast;

    const int n    = blockIdx.x;
    const int tid  = threadIdx.x;
    const int lane = tid & 63;
    const int wid  = tid >> 6;
    const int col  = lane & 15;   // MFMA col (point) / A-row index
    const int grp  = lane >> 4;   // k-slot group / output-plane selector

    const float* __restrict__ w0n = w0 + (size_t)n * HDIM;
    const float* __restrict__ b0n = b0 + (size_t)n * HDIM;
    const float* __restrict__ w1n = w1 + (size_t)n * HDIM * HDIM;
    const float* __restrict__ b1n = b1 + (size_t)n * HDIM;
    const float* __restrict__ w2n = w2 + (size_t)n * 2 * HDIM;
    const float* __restrict__ b2n = b2 + (size_t)n * 2;

    // ---- stage trig table, tanh table, and 256*W1 (bf16, XOR swizzle) ----
    for (int e = tid; e < NHALF; e += 256) {
        const float xx = alpha[e];
        const float cc = __cosf(xx);
        f32x4 t; t.x = xx; t.y = __sinf(xx); t.z = cc - 1.0f; t.w = cc;
        s_trig[e] = t;
    }
    for (int e = tid; e < 2048; e += 256) {
        const float z = (float)(e - 1024) * 0.00390625f;     // 1/256
        const float ee = __builtin_amdgcn_exp2f(z * C2L);
        s_tanh[e] = fmaf(-2.0f, __builtin_amdgcn_rcpf(1.0f + ee), 1.0f);  // tanh(z)
    }
    for (int e4 = tid; e4 < (HDIM * HDIM) / 4; e4 += 256) {
        const int i = e4 >> 4, j4 = (e4 & 15) << 2;
        f32x4 v = ((const f32x4*)w1n)[e4];
        bf16x4 b;
        b[0] = (__bf16)(v.x * 256.0f); b[1] = (__bf16)(v.y * 256.0f);
        b[2] = (__bf16)(v.z * 256.0f); b[3] = (__bf16)(v.w * 256.0f);
        *(bf16x4*)&w1s[i * 64 + (((j4 >> 3) ^ (i & 7)) << 3) + (j4 & 7)] = b;
    }
    __syncthreads();

    // ---- constants for packed math ----
    const f32x2 _k1 = {1.0f, 1.0f};

    // ---- per-lane hoisted constants ----
    const int jb0 = grp * 8, jb1 = 32 + grp * 8;
    f32x4 w0iA = *(const f32x4*)(w0n + jb0);
    f32x4 w0iB = *(const f32x4*)(w0n + jb0 + 4);
    f32x4 w0iC = *(const f32x4*)(w0n + jb1);
    f32x4 w0iD = *(const f32x4*)(w0n + jb1 + 4);
    const f32x4 w0dA = w0iA * 0.00390625f;   // w0/256 (tangent-scale compensation)
    const f32x4 w0dB = w0iB * 0.00390625f;
    const f32x4 w0dC = w0iC * 0.00390625f;
    const f32x4 w0dD = w0iD * 0.00390625f;
    w0iA *= 256.0f; w0iB *= 256.0f; w0iC *= 256.0f; w0iD *= 256.0f;
    f32x4 b0iA = *(const f32x4*)(b0n + jb0);
    f32x4 b0iB = *(const f32x4*)(b0n + jb0 + 4);
    f32x4 b0iC = *(const f32x4*)(b0n + jb1);
    f32x4 b0iD = *(const f32x4*)(b0n + jb1 + 4);
    b0iA = b0iA * 256.0f + 1024.5f; b0iB = b0iB * 256.0f + 1024.5f;
    b0iC = b0iC * 256.0f + 1024.5f; b0iD = b0iD * 256.0f + 1024.5f;

    f32x4 b1i0 = *(const f32x4*)(b1n + 0  + grp * 4);
    f32x4 b1i1 = *(const f32x4*)(b1n + 16 + grp * 4);
    f32x4 b1i2 = *(const f32x4*)(b1n + 32 + grp * 4);
    f32x4 b1i3 = *(const f32x4*)(b1n + 48 + grp * 4);
    b1i0 = b1i0 * 256.0f + 1024.5f; b1i1 = b1i1 * 256.0f + 1024.5f;
    b1i2 = b1i2 * 256.0f + 1024.5f; b1i3 = b1i3 * 256.0f + 1024.5f;

    const f32x4 w2a0 = *(const f32x4*)(w2n + 0  + grp * 4);
    const f32x4 w2a1 = *(const f32x4*)(w2n + 16 + grp * 4);
    const f32x4 w2a2 = *(const f32x4*)(w2n + 32 + grp * 4);
    const f32x4 w2a3 = *(const f32x4*)(w2n + 48 + grp * 4);
    const f32x4 w2b0 = *(const f32x4*)(w2n + 64 + 0  + grp * 4);
    const f32x4 w2b1 = *(const f32x4*)(w2n + 64 + 16 + grp * 4);
    const f32x4 w2b2 = *(const f32x4*)(w2n + 64 + 32 + grp * 4);
    const f32x4 w2b3 = *(const f32x4*)(w2n + 64 + 48 + grp * 4);
    const float b20 = b2n[0], b21 = b2n[1];

    // ---- A-fragments: 256*W1 rows in registers ----
    const bf16x8* w1v = (const bf16x8*)w1s;
    const int sw = col & 7;
#define AF(RT,KH) w1v[((RT)*16 + col)*8 + (((KH)*4 + grp) ^ sw)]
    const bf16x8 A00 = AF(0,0), A01 = AF(0,1), A10 = AF(1,0), A11 = AF(1,1);
    const bf16x8 A20 = AF(2,0), A21 = AF(2,1), A30 = AF(3,0), A31 = AF(3,1);

    const size_t obase = (size_t)grp * PLANE + (size_t)n * NFULL;

    // ---- point 1024 first (wave 0), to get xp_last for the xp mirror ----
    if (wid == 0) {
        COMPUTE_TILE(1024)
        if (col == 0) {
            out[obase + 1024] = (grp == 0) ? xp : (grp == 1) ? yp : (grp == 2) ? xpp : ypp;
            if (grp == 0) s_xplast = xp;
        }
    }
    __syncthreads();
    const float xl2 = 2.0f * s_xplast;

    // ---- main loop: 16 iters/wave, 16 points each; covers b = 0..1023 ----
    #pragma unroll 1
    for (int it = 0; it < 16; ++it) {
        const int p = ((it * 4 + wid) << 4) + col;
        COMPUTE_TILE(p)
        const float vdir = (grp == 0) ? xp : (grp == 1) ? yp : (grp == 2) ? xpp : ypp;
        const float vmir = (grp == 0) ? (xl2 - xp)
                         : (grp == 1) ? yp
                         : (grp == 2) ? xpp : -ypp;
        out[obase + p] = vdir;
        out[obase + (2048 - p)] = vmir;
    }
}

extern "C" void kernel_launch(void* const* d_in, const int* in_sizes, int n_in,
                              void* d_out, int out_size, void* d_ws, size_t ws_size,
                              hipStream_t stream) {
    const float* alpha = (const float*)d_in[0];
    const float* w0    = (const float*)d_in[1];
    const float* w1    = (const float*)d_in[2];
    const float* w2    = (const float*)d_in[3];
    const float* b0    = (const float*)d_in[4];
    const float* b1    = (const float*)d_in[5];
    const float* b2    = (const float*)d_in[6];
    float* out = (float*)d_out;
    sofa_kernel<<<dim3(N_AB), dim3(256), 0, stream>>>(alpha, w0, w1, w2, b0, b1, b2, out);
}